// Round 13
// baseline (250.680 us; speedup 1.0000x reference)
//
#include <hip/hip_runtime.h>
#include <hip/hip_fp16.h>

namespace {

constexpr int T_STEPS = 256;
constexpr int HD = 50;    // hidden size
constexpr int HP = 64;    // padded hidden
constexpr int KST = 88;   // h-buf row stride in fp16 elems
constexpr int KSTS = 72;  // weight staging stride
constexpr int BT = 8;     // batch tile per block (halved: 2 blocks/CU for barrier desync)
constexpr int NTHR = 768; // 12 waves: (layer, M-tile)
constexpr int XST = 18;   // xls row stride in floats (even -> 8B-aligned float2)
constexpr int LAY_SH = BT * KST;     // shorts per (slot, layer) = 704
constexpr int SLOT_SH = 3 * LAY_SH;  // shorts per ring slot = 2112

typedef __attribute__((ext_vector_type(8))) _Float16 f16x8;
typedef __attribute__((ext_vector_type(4))) float f32x4;

__device__ __forceinline__ unsigned short f2h(float x) {
  __half h = __float2half(x);  // RNE
  return *reinterpret_cast<unsigned short*>(&h);
}
__device__ __forceinline__ float h2f(unsigned short u) {
  __half h;
  *reinterpret_cast<unsigned short*>(&h) = u;
  return __half2float(h);
}

#define MFMA16 __builtin_amdgcn_mfma_f32_16x16x32_f16

// R8 data path (12 waves = layer x M-tile, fp16 h/W, diagonal 0/2/4, 3-slot
// ring, literal-slot unroll, batched-rcp tanh, per-iter __syncthreads) at
// HALF batch tile: BT=8, grid=512 -> 2 co-resident blocks per CU. Each block's
// barrier gates only its own 12 waves, so block B fills the LDS/VALU/trans
// pipes while block A sits at its barrier (R8: no pipe >65% busy — the
// residue was barrier phase-alignment, unfixable within one block: R9-R11).
// N=16 MFMA tile half-wasted (MfmaUtil was 13% — irrelevant); B-reads use
// col=l15&7 -> lane pairs read SAME address = LDS broadcast (read bank
// traffic halves); h-writes exec-masked to l15<8 (write traffic halves).
__global__ __launch_bounds__(NTHR, 6) void rnn3_kernel(
    const float* __restrict__ x,
    const float* __restrict__ Wih1, const float* __restrict__ Whh1,
    const float* __restrict__ bih1, const float* __restrict__ bhh1,
    const float* __restrict__ Wih2, const float* __restrict__ Whh2,
    const float* __restrict__ bih2, const float* __restrict__ bhh2,
    const float* __restrict__ Wih3, const float* __restrict__ Whh3,
    const float* __restrict__ bih3, const float* __restrict__ bhh3,
    const float* __restrict__ fcw, const float* __restrict__ fcb,
    float* __restrict__ out) {
  __shared__ unsigned short hbuf[3 * SLOT_SH];  // [ring][layer][b*KST+k], fp16 bits
  __shared__ float xls[T_STEPS][XST];           // staged x (8 cols)
  __shared__ unsigned short scr[HP * KSTS];     // weight staging (fp16)

  const int tid = threadIdx.x;
  const int w = tid >> 6;
  const int myL = w >> 2;        // layer 0..2
  const int wv = w & 3;          // M-tile
  const int lane = tid & 63;
  const int quad = lane >> 4;
  const int l15 = lane & 15;
  const int bcol = l15 & 7;      // batch column (lanes l15 and l15+8 duplicate -> LDS broadcast)
  const int b0 = blockIdx.x * BT;

  // zero all 3 ring slots (initial h=0 and the k>=HD pad)
  {
    unsigned int* hz = reinterpret_cast<unsigned int*>(hbuf);
    const int n = 3 * SLOT_SH / 2;
    for (int i = tid; i < n; i += NTHR) hz[i] = 0u;
  }
  // stage x -> LDS (8 batch columns)
  for (int idx = tid; idx < BT * T_STEPS; idx += NTHR) {
    int b = idx >> 8, t = idx & 255;
    float2 v = *reinterpret_cast<const float2*>(x + (size_t)(b0 + b) * (T_STEPS * 2) + 2 * t);
    xls[t][2 * b] = v.x;
    xls[t][2 * b + 1] = v.y;
  }

  // ---- stage the five 50x50 matrices as fp16 ----
  const float* mats[5] = {Whh1, Wih2, Whh2, Wih3, Whh3};
  constexpr int matL[5] = {0, 1, 1, 2, 2};
  constexpr int matS[5] = {0, 0, 1, 0, 1};  // slot0 = cross (self for L0), slot1 = self
  f16x8 wA[2][2];  // [slot][kstep]
#pragma unroll
  for (int sl = 0; sl < 2; ++sl)
#pragma unroll
    for (int ks = 0; ks < 2; ++ks) wA[sl][ks] = f16x8(0);

  const int arow = 16 * wv + l15;
#pragma unroll
  for (int m = 0; m < 5; ++m) {
    __syncthreads();
    const float* W = mats[m];
    for (int idx = tid; idx < HP * HP; idx += NTHR) {
      int i = idx >> 6, k = idx & 63;
      float v = (i < HD && k < HD) ? W[i * HD + k] : 0.0f;
      scr[i * KSTS + k] = f2h(v);
    }
    __syncthreads();
    if (myL == matL[m]) {
      const int sl = matS[m];
      const unsigned short* ph = &scr[arow * KSTS + 8 * quad];
      wA[sl][0] = *reinterpret_cast<const f16x8*>(ph);
      wA[sl][1] = *reinterpret_cast<const f16x8*>(ph + 32);
    }
  }

  // per-lane C-row constants
  const int ic = 16 * wv + 4 * quad;
  const float* bi = (myL == 0) ? bih1 : (myL == 1) ? bih2 : bih3;
  const float* bh = (myL == 0) ? bhh1 : (myL == 1) ? bhh2 : bhh3;
  float wx0[4], wx1[4];
  f32x4 bsv;
#pragma unroll
  for (int r = 0; r < 4; ++r) {
    int i = ic + r;
    bool v = i < HD;
    bsv[r] = v ? (bi[i] + bh[i]) : 0.0f;
    wx0[r] = (v && myL == 0) ? Wih1[i * 2 + 0] : 0.0f;
    wx1[r] = (v && myL == 0) ? Wih1[i * 2 + 1] : 0.0f;
  }

  const int selfBuf = myL;
  const int crossBuf = (myL > 0) ? myL - 1 : 0;
  const int ldsOff = bcol * KST + 8 * quad;   // broadcast-paired read offset

  const unsigned short* sbase = hbuf + selfBuf * LAY_SH + ldsOff;
  const unsigned short* cbase = hbuf + crossBuf * LAY_SH + ldsOff;
  unsigned short* wbase = hbuf + myL * LAY_SH + l15 * KST + ic;  // only l15<8 writes

  f16x8 pfC0 = f16x8(0), pfC1 = f16x8(0);  // cross B-frags for CURRENT iter

  __syncthreads();

  // ---- compute core for one diagonal step (R8 form) ----
  auto core = [&](int s, int wr, int rd) {
    f16x8 bS0 = *reinterpret_cast<const f16x8*>(sbase + rd * SLOT_SH);
    f16x8 bS1 = *reinterpret_cast<const f16x8*>(sbase + rd * SLOT_SH + 32);
    f16x8 pfN0, pfN1;
    if (myL > 0) {  // prefetch cross frags for NEXT iter
      pfN0 = *reinterpret_cast<const f16x8*>(cbase + rd * SLOT_SH);
      pfN1 = *reinterpret_cast<const f16x8*>(cbase + rd * SLOT_SH + 32);
    }
    f32x4 c;
    if (myL == 0) {
      float2 xc = *reinterpret_cast<const float2*>(&xls[s][2 * bcol]);
      f32x4 ci;
#pragma unroll
      for (int r = 0; r < 4; ++r) ci[r] = fmaf(wx1[r], xc.y, fmaf(wx0[r], xc.x, bsv[r]));
      c = MFMA16(wA[0][0], bS0, ci, 0, 0, 0);
      c = MFMA16(wA[0][1], bS1, c, 0, 0, 0);
    } else {
      c = MFMA16(wA[0][0], pfC0, bsv, 0, 0, 0);
      c = MFMA16(wA[0][1], pfC1, c, 0, 0, 0);
      c = MFMA16(wA[1][0], bS0, c, 0, 0, 0);
      c = MFMA16(wA[1][1], bS1, c, 0, 0, 0);
    }
    // batched tanh: ONE rcp for 4 values; clamp keeps product < f32-max
    float d[4];
#pragma unroll
    for (int r = 0; r < 4; ++r) {
      float xr = __builtin_amdgcn_fmed3f(c[r], -11.0f, 11.0f);
      d[r] = __expf(2.0f * xr) + 1.0f;
    }
    float p01 = d[0] * d[1], p23 = d[2] * d[3];
    float rp = __builtin_amdgcn_rcpf(p01 * p23);
    float q01 = rp * p23, q23 = rp * p01;
    float iv[4] = {q01 * d[1], q01 * d[0], q23 * d[3], q23 * d[2]};
    unsigned short ht[4];
#pragma unroll
    for (int r = 0; r < 4; ++r) ht[r] = f2h(fmaf(-2.0f, iv[r], 1.0f));
    if (l15 < 8) {  // cols 8..15 are duplicates — don't write them back
      unsigned int h01 = (unsigned int)ht[0] | ((unsigned int)ht[1] << 16);
      unsigned int h23 = (unsigned int)ht[2] | ((unsigned int)ht[3] << 16);
      *reinterpret_cast<uint2*>(wbase + wr * SLOT_SH) = make_uint2(h01, h23);
    }
    if (myL > 0) { pfC0 = pfN0; pfC1 = pfN1; }
  };

  auto actOf = [&](int s) {
    return (myL == 0) ? (s < T_STEPS)
         : (myL == 1) ? (s >= 2 && s < T_STEPS + 2)
                      : (s >= 4);
  };

  auto stepB = [&](int s, int wr, int rd, bool act) {
    if (act) core(s, wr, rd);
    else if (myL > 0) {  // keep cross prefetch alive through inactive iters
      pfC0 = *reinterpret_cast<const f16x8*>(cbase + rd * SLOT_SH);
      pfC1 = *reinterpret_cast<const f16x8*>(cbase + rd * SLOT_SH + 32);
    }
    __syncthreads();
  };

  // prologue s=0..3
  for (int s = 0; s < 4; ++s) stepB(s, s % 3, (s + 2) % 3, actOf(s));
  // steady s=4..255: all waves active; literal ring slots
  for (int sb = 4; sb < 256; sb += 3) {
    core(sb + 0, 1, 0); __syncthreads();
    core(sb + 1, 2, 1); __syncthreads();
    core(sb + 2, 0, 2); __syncthreads();
  }
  // epilogue s=256..259
  for (int s = 256; s < 260; ++s) stepB(s, s % 3, (s + 2) % 3, actOf(s));

  // ---- fc epilogue: h3_255 written at s=259 -> slot 259%3 = 1 ----
  if (tid < BT * 2) {
    int b = tid >> 1, o = tid & 1;
    const unsigned short* h3 = hbuf + 1 * SLOT_SH + 2 * LAY_SH + b * KST;
    float acc = fcb[o];
    for (int i = 0; i < HD; ++i) acc += fcw[o * HD + i] * h2f(h3[i]);
    out[(size_t)(b0 + b) * 2 + o] = acc;
  }
}

}  // namespace

extern "C" void kernel_launch(void* const* d_in, const int* in_sizes, int n_in,
                              void* d_out, int out_size, void* d_ws, size_t ws_size,
                              hipStream_t stream) {
  const float* x = (const float*)d_in[0];
  const float* Wih1 = (const float*)d_in[1];
  const float* Whh1 = (const float*)d_in[2];
  const float* bih1 = (const float*)d_in[3];
  const float* bhh1 = (const float*)d_in[4];
  const float* Wih2 = (const float*)d_in[5];
  const float* Whh2 = (const float*)d_in[6];
  const float* bih2 = (const float*)d_in[7];
  const float* bhh2 = (const float*)d_in[8];
  const float* Wih3 = (const float*)d_in[9];
  const float* Whh3 = (const float*)d_in[10];
  const float* bih3 = (const float*)d_in[11];
  const float* bhh3 = (const float*)d_in[12];
  const float* fcw = (const float*)d_in[13];
  const float* fcb = (const float*)d_in[14];

  rnn3_kernel<<<4096 / BT, NTHR, 0, stream>>>(x, Wih1, Whh1, bih1, bhh1,
                                              Wih2, Whh2, bih2, bhh2,
                                              Wih3, Whh3, bih3, bhh3,
                                              fcw, fcb, (float*)d_out);
}